// Round 4
// baseline (831.167 us; speedup 1.0000x reference)
//
#include <hip/hip_runtime.h>
#include <cstddef>

// ---------------------------------------------------------------------------
// RQ-VAE forward, bf16-MFMA pipeline.
//   prep:  weights -> Wt bf16 [N][K]; codebooks -> bf16 + f32 norms
//   G1: H1 = gelu(x @ eW1 + eb1)          (A: f32->bf16 in-flight)   -> bf16
//   G2: Z  = H1 @ eW2 + eb2                                           -> f32
//   VQ: 3 stages; 512thr/64rows, residual f32 in regs (32/thread),
//       scoring = reg A-frags x codebook B-frags direct from L2 (no
//       barriers in the loop); emits ZQ = q0+q1+q2 as bf16
//   G3: H2 = gelu(ZQ @ dW1 + db1)                                     -> bf16
//   G4: recon = mean((H2 @ dW2 + db2 - x)^2)   (loss-only epilogue)
// ---------------------------------------------------------------------------

typedef __attribute__((ext_vector_type(8))) __bf16 bf16x8;
typedef __attribute__((ext_vector_type(4))) float f32x4;
typedef unsigned short u16;

__device__ __forceinline__ u16 f2bf(float f) {
    unsigned u = __float_as_uint(f);
    u += 0x7fffu + ((u >> 16) & 1u);      // round-to-nearest-even
    return (u16)(u >> 16);
}
__device__ __forceinline__ float gelu_exact(float v) {
    return 0.5f * v * (1.0f + erff(v * 0.7071067811865475f));
}
__device__ __forceinline__ void gload16(const void* g, void* l) {
    __builtin_amdgcn_global_load_lds(
        (const __attribute__((address_space(1))) void*)g,
        (__attribute__((address_space(3))) void*)l, 16, 0, 0);
}
__device__ __forceinline__ f32x4 mfma_bf16(bf16x8 a, bf16x8 b, f32x4 c) {
    return __builtin_amdgcn_mfma_f32_16x16x32_bf16(a, b, c, 0, 0, 0);
}

// ---------------------------------------------------------------------------
// prep: transpose+cast the 4 weights to bf16 [N][K]
__global__ __launch_bounds__(256)
void prep_weights(const float* __restrict__ eW1, const float* __restrict__ eW2,
                  const float* __restrict__ dW1, const float* __restrict__ dW2,
                  u16* __restrict__ eW1t, u16* __restrict__ eW2t,
                  u16* __restrict__ dW1t, u16* __restrict__ dW2t)
{
    const int b = blockIdx.x, t = threadIdx.x;
    if (b < 2048) {                    // eW1 [1024][512] -> [512][1024]
        int e = b * 256 + t;
        int n = e >> 10, k = e & 1023;
        eW1t[e] = f2bf(eW1[(size_t)k * 512 + n]);
    } else if (b < 2560) {             // eW2 [512][256] -> [256][512]
        int e = (b - 2048) * 256 + t;
        int n = e >> 9, k = e & 511;
        eW2t[e] = f2bf(eW2[(size_t)k * 256 + n]);
    } else if (b < 3072) {             // dW1 [256][512] -> [512][256]
        int e = (b - 2560) * 256 + t;
        int n = e >> 8, k = e & 255;
        dW1t[e] = f2bf(dW1[(size_t)k * 512 + n]);
    } else {                           // dW2 [512][1024] -> [1024][512]
        int e = (b - 3072) * 256 + t;
        int n = e >> 9, k = e & 511;
        dW2t[e] = f2bf(dW2[(size_t)k * 1024 + n]);
    }
}

// codebooks: bf16 cast (contiguous [1792][256]) + f32 squared norms
__global__ __launch_bounds__(256)
void cb_prep(const float* __restrict__ C0, const float* __restrict__ C1,
             const float* __restrict__ C2, u16* __restrict__ Cbf,
             float* __restrict__ cnorm)
{
    __shared__ float red[256];
    const int code = blockIdx.x, t = threadIdx.x;
    const float* C;
    int local;
    if (code < 1024)      { C = C0; local = code; }
    else if (code < 1536) { C = C1; local = code - 1024; }
    else                  { C = C2; local = code - 1536; }
    const float v = C[(size_t)local * 256 + t];
    Cbf[(size_t)code * 256 + t] = f2bf(v);
    red[t] = v * v;
    __syncthreads();
    for (int s = 128; s; s >>= 1) { if (t < s) red[t] += red[t + s]; __syncthreads(); }
    if (t == 0) cnorm[code] = red[0];
}

// ---------------------------------------------------------------------------
// MFMA GEMM: C = A[M,K] @ Bt[N,K]^T, 128x128 tile, BK=32, 4 waves, dbuf LDS.
// EPI: 0 = gelu -> bf16 store, 1 = plain -> f32 store, 2 = sq-err loss vs X
// AF32: A is f32, converted to bf16 during staging (reg path).
template <int EPI, bool AF32>
__global__ __launch_bounds__(256, 2)
void gemm_mfma(const void* __restrict__ Aptr, const u16* __restrict__ Bt,
               const float* __restrict__ bias, u16* __restrict__ Obf,
               float* __restrict__ Of, const float* __restrict__ X,
               float* __restrict__ lossOut, int N, int K, int ntn,
               float lossScale)
{
    __shared__ __align__(16) u16 As[2][128 * 32];
    __shared__ __align__(16) u16 Bs[2][128 * 32];

    const int nwg = gridDim.x;
    const int bid = blockIdx.x;
    const int wg  = (bid & 7) * (nwg >> 3) + (bid >> 3);   // XCD-chunked swizzle
    const int brow = (wg / ntn) * 128;
    const int bcol = (wg % ntn) * 128;

    const int t    = threadIdx.x;
    const int lane = t & 63;
    const int wid  = t >> 6;
    const int wrow = (wid >> 1) * 64, wcol = (wid & 1) * 64;
    const int lrow = lane & 15, lk8 = (lane >> 4) * 8;

    const int nt = K >> 5;   // K-steps of 32

    f32x4 acc[4][4];
#pragma unroll
    for (int m = 0; m < 4; ++m)
#pragma unroll
        for (int n = 0; n < 4; ++n) acc[m][n] = (f32x4)0.f;

    const u16*   Abf = (const u16*)Aptr;
    const float* Af  = (const float*)Aptr;

    // ---- staging helpers ----
    auto stageB = [&](int kt, int buf) {
#pragma unroll
        for (int it = 0; it < 2; ++it) {
            const int e0 = (it * 256 + t) * 8;
            const int row = e0 >> 5, col = e0 & 31;
            gload16(&Bt[(size_t)(bcol + row) * K + kt * 32 + col],
                    (char*)&Bs[buf][0] + (size_t)e0 * 2);
        }
    };
    auto stageA_bf = [&](int kt, int buf) {
#pragma unroll
        for (int it = 0; it < 2; ++it) {
            const int e0 = (it * 256 + t) * 8;
            const int row = e0 >> 5, col = e0 & 31;
            gload16(&Abf[(size_t)(brow + row) * K + kt * 32 + col],
                    (char*)&As[buf][0] + (size_t)e0 * 2);
        }
    };
    auto issueA_f32 = [&](int kt, float4* r) {
#pragma unroll
        for (int it = 0; it < 4; ++it) {
            const int e0 = (it * 256 + t) * 4;
            const int row = e0 >> 5, col = e0 & 31;
            r[it] = *(const float4*)&Af[(size_t)(brow + row) * K + kt * 32 + col];
        }
    };
    auto writeA_f32 = [&](int buf, const float4* r) {
#pragma unroll
        for (int it = 0; it < 4; ++it) {
            const int e0 = (it * 256 + t) * 4;
            const float4 v = r[it];
            unsigned lo = (unsigned)f2bf(v.x) | ((unsigned)f2bf(v.y) << 16);
            unsigned hi = (unsigned)f2bf(v.z) | ((unsigned)f2bf(v.w) << 16);
            *(uint2*)((char*)&As[buf][0] + (size_t)e0 * 2) = make_uint2(lo, hi);
        }
    };

    // ---- prologue ----
    if (AF32) {
        float4 r0[4];
        issueA_f32(0, r0);
        stageB(0, 0);
        writeA_f32(0, r0);
    } else {
        stageA_bf(0, 0);
        stageB(0, 0);
    }
    __syncthreads();

    int cur = 0;
    for (int kt = 0; kt < nt; ++kt) {
        const bool last = (kt == nt - 1);
        float4 rnext[4];
        if (!last) {
            if (AF32) issueA_f32(kt + 1, rnext);
            else      stageA_bf(kt + 1, cur ^ 1);
            stageB(kt + 1, cur ^ 1);
        }
        // compute current buffer
        bf16x8 a[4], b[4];
#pragma unroll
        for (int m = 0; m < 4; ++m)
            a[m] = *(const bf16x8*)&As[cur][(wrow + m * 16 + lrow) * 32 + lk8];
#pragma unroll
        for (int n = 0; n < 4; ++n)
            b[n] = *(const bf16x8*)&Bs[cur][(wcol + n * 16 + lrow) * 32 + lk8];
#pragma unroll
        for (int m = 0; m < 4; ++m)
#pragma unroll
            for (int n = 0; n < 4; ++n)
                acc[m][n] = mfma_bf16(a[m], b[n], acc[m][n]);

        if (AF32 && !last) writeA_f32(cur ^ 1, rnext);
        __syncthreads();
        cur ^= 1;
    }

    // ---- epilogue ----
    int   colN[4];
    float bn[4];
#pragma unroll
    for (int n = 0; n < 4; ++n) {
        colN[n] = bcol + wcol + n * 16 + lrow;
        bn[n]   = bias[colN[n]];
    }

    if (EPI == 0) {
#pragma unroll
        for (int m = 0; m < 4; ++m) {
            const int rowb = brow + wrow + m * 16 + (lane >> 4) * 4;
#pragma unroll
            for (int n = 0; n < 4; ++n)
#pragma unroll
                for (int j = 0; j < 4; ++j)
                    Obf[(size_t)(rowb + j) * N + colN[n]] =
                        f2bf(gelu_exact(acc[m][n][j] + bn[n]));
        }
    } else if (EPI == 1) {
#pragma unroll
        for (int m = 0; m < 4; ++m) {
            const int rowb = brow + wrow + m * 16 + (lane >> 4) * 4;
#pragma unroll
            for (int n = 0; n < 4; ++n)
#pragma unroll
                for (int j = 0; j < 4; ++j)
                    Of[(size_t)(rowb + j) * N + colN[n]] = acc[m][n][j] + bn[n];
        }
    } else {
        float partial = 0.f;
#pragma unroll
        for (int m = 0; m < 4; ++m) {
            const int rowb = brow + wrow + m * 16 + (lane >> 4) * 4;
#pragma unroll
            for (int n = 0; n < 4; ++n)
#pragma unroll
                for (int j = 0; j < 4; ++j) {
                    const float o = acc[m][n][j] + bn[n];
                    const float d = o - X[(size_t)(rowb + j) * N + colN[n]];
                    partial = fmaf(d, d, partial);
                }
        }
        float* red = (float*)&As[0][0];
        red[t] = partial;
        __syncthreads();
        for (int s = 128; s; s >>= 1) { if (t < s) red[t] += red[t + s]; __syncthreads(); }
        if (t == 0) atomicAdd(lossOut, red[0] * lossScale);
    }
}

// ---------------------------------------------------------------------------
// VQ v4: 512 threads, 64 rows/block. Thread (col = t&255, rh = t>>8) owns
// rows rh*32..rh*32+31 of column col -> R[32] f32 in regs (no spill).
// 8 waves = 4 row-groups x 2 code-halves. Per stage:
//   - bf16 mirror of R into LDS; wave loads its 16-row A-frags to regs
//   - scoring: B-frags read DIRECTLY from L2-resident bf16 codebook
//     (no LDS staging, no barriers in the loop; unroll-2 chunks in flight)
//   - wave argmin over 16 code-lanes, cross-wave combine over code-halves
//   - f32 residual update + commit loss
// Final: ZQ = C0[i0]+C1[i1]+C2[i2] (no Z re-read).
__global__ __launch_bounds__(512, 4)
void vq_mfma(const float* __restrict__ Z, const u16* __restrict__ Cbf,
             const float* __restrict__ cnorm,
             const float* __restrict__ C0, const float* __restrict__ C1,
             const float* __restrict__ C2,
             u16* __restrict__ ZQ, float* __restrict__ lossOut)
{
    __shared__ __align__(16) u16 Rb[64][264];   // 528B row stride: 4-bank step
    __shared__ float redv[64][2];
    __shared__ int   redi[64][2];
    __shared__ int   idxs[3][64];
    __shared__ float lred[512];

    const int t    = threadIdx.x;
    const int lane = t & 63;
    const int wid  = t >> 6;           // 0..7
    const int rg   = wid & 3;          // row group (16 rows)
    const int cg   = wid >> 2;         // code half
    const int lrow = lane & 15, g = lane >> 4;
    const int col  = t & 255;          // owned column
    const int rh   = t >> 8;           // row half (32 rows)
    const int brow = blockIdx.x * 64;

    float R[32];
#pragma unroll
    for (int r = 0; r < 32; ++r)
        R[r] = Z[(size_t)(brow + rh * 32 + r) * 256 + col];

    const float* Cf[3]  = {C0, C1, C2};
    const int ncodes[3] = {1024, 512, 256};
    const int coff[3]   = {0, 1024, 1536};
    const float lscale  = 1.25f / (65536.0f * 256.0f);

    for (int stage = 0; stage < 3; ++stage) {
        // 1) bf16 mirror of residual
#pragma unroll
        for (int r = 0; r < 32; ++r) Rb[rh * 32 + r][col] = f2bf(R[r]);
        __syncthreads();

        // 2) wave's 16 rows -> A fragments in registers for the whole stage
        bf16x8 a[8];
#pragma unroll
        for (int ks = 0; ks < 8; ++ks)
            a[ks] = *(const bf16x8*)&Rb[rg * 16 + lrow][ks * 32 + g * 8];

        float best[4]; int bidx[4];
#pragma unroll
        for (int j = 0; j < 4; ++j) { best[j] = 3.0e38f; bidx[j] = 0; }

        const u16*   Cb  = Cbf + (size_t)coff[stage] * 256;
        const float* cns = cnorm + coff[stage];
        const int nch = ncodes[stage] >> 5;   // chunks of 32 codes (16/wave)

#pragma unroll 2
        for (int ch = 0; ch < nch; ++ch) {
            const int code = ch * 32 + cg * 16 + lrow;   // this lane's code
            const float cn = cns[code];
            const u16* bp = &Cb[(size_t)code * 256 + g * 8];
            f32x4 acc = (f32x4)0.f;
#pragma unroll
            for (int ks = 0; ks < 8; ++ks)
                acc = mfma_bf16(a[ks], *(const bf16x8*)&bp[ks * 32], acc);
#pragma unroll
            for (int j = 0; j < 4; ++j) {
                const float s = fmaf(-2.0f, acc[j], cn);
                if (s < best[j]) { best[j] = s; bidx[j] = code; }
            }
        }

        // 3) argmin: 16 code-lanes within wave, then across the 2 code-halves
#pragma unroll
        for (int j = 0; j < 4; ++j) {
            float v = best[j]; int i = bidx[j];
#pragma unroll
            for (int d = 1; d < 16; d <<= 1) {
                const float ov = __shfl_xor(v, d);
                const int   oi = __shfl_xor(i, d);
                if (ov < v || (ov == v && oi < i)) { v = ov; i = oi; }
            }
            if (lrow == 0) {
                redv[rg * 16 + g * 4 + j][cg] = v;
                redi[rg * 16 + g * 4 + j][cg] = i;
            }
        }
        __syncthreads();
        if (t < 64) {
            float v = redv[t][0]; int i = redi[t][0];
            const float ov = redv[t][1]; const int oi = redi[t][1];
            if (ov < v || (ov == v && oi < i)) { v = ov; i = oi; }
            idxs[stage][t] = i;
        }
        __syncthreads();

        // 4) residual update + commit loss (f32, thread owns its column)
        const float* Cfs = Cf[stage];
        float partial = 0.f;
#pragma unroll
        for (int r = 0; r < 32; ++r) {
            const float q  = Cfs[(size_t)idxs[stage][rh * 32 + r] * 256 + col];
            const float rn = R[r] - q;
            R[r] = rn;
            partial = fmaf(rn, rn, partial);
        }
        lred[t] = partial;
        __syncthreads();
        for (int s = 256; s; s >>= 1) { if (t < s) lred[t] += lred[t + s]; __syncthreads(); }
        if (t == 0) atomicAdd(&lossOut[1 + stage], lred[0] * lscale);
        __syncthreads();
    }

    // 5) ZQ = q0 + q1 + q2 (f32 gather from L2-resident codebooks), bf16
#pragma unroll
    for (int r = 0; r < 32; ++r) {
        const int row = rh * 32 + r;
        const float zq = C0[(size_t)idxs[0][row] * 256 + col]
                       + C1[(size_t)idxs[1][row] * 256 + col]
                       + C2[(size_t)idxs[2][row] * 256 + col];
        ZQ[(size_t)(brow + row) * 256 + col] = f2bf(zq);
    }
}

// ---------------------------------------------------------------------------
extern "C" void kernel_launch(void* const* d_in, const int* in_sizes, int n_in,
                              void* d_out, int out_size, void* d_ws, size_t ws_size,
                              hipStream_t stream)
{
    const float* x   = (const float*)d_in[0];
    const float* eW1 = (const float*)d_in[1];
    const float* eb1 = (const float*)d_in[2];
    const float* eW2 = (const float*)d_in[3];
    const float* eb2 = (const float*)d_in[4];
    const float* dW1 = (const float*)d_in[5];
    const float* db1 = (const float*)d_in[6];
    const float* dW2 = (const float*)d_in[7];
    const float* db2 = (const float*)d_in[8];
    const float* C0  = (const float*)d_in[9];
    const float* C1  = (const float*)d_in[10];
    const float* C2  = (const float*)d_in[11];
    float* out = (float*)d_out;

    char* w = (char*)d_ws;
    u16*   H1   = (u16*)(w);                          // 64 MiB
    float* Zf   = (float*)(w + ((size_t)64 << 20));   // 64 MiB
    u16*   ZQ   = (u16*)(w + ((size_t)128 << 20));    // 32 MiB
    u16*   H2   = (u16*)(w + ((size_t)160 << 20));    // 64 MiB
    u16*   eW1t = (u16*)(w + ((size_t)224 << 20));
    u16*   eW2t = (u16*)(w + ((size_t)225 << 20));
    u16*   dW1t = (u16*)(w + ((size_t)226 << 20));
    u16*   dW2t = (u16*)(w + ((size_t)227 << 20));
    u16*   Cbf  = (u16*)(w + ((size_t)228 << 20));
    float* cn   = (float*)(w + ((size_t)229 << 20));

    hipMemsetAsync(d_out, 0, 4 * sizeof(float), stream);

    prep_weights<<<5120, 256, 0, stream>>>(eW1, eW2, dW1, dW2, eW1t, eW2t, dW1t, dW2t);
    cb_prep<<<1792, 256, 0, stream>>>(C0, C1, C2, Cbf, cn);

    // G1: H1 = gelu(x @ eW1 + eb1)    M=65536 N=512 K=1024, A f32
    gemm_mfma<0, true><<<2048, 256, 0, stream>>>(
        x, eW1t, eb1, H1, nullptr, nullptr, nullptr, 512, 1024, 4, 0.f);
    // G2: Z = H1 @ eW2 + eb2          M=65536 N=256 K=512
    gemm_mfma<1, false><<<1024, 256, 0, stream>>>(
        H1, eW2t, eb2, nullptr, Zf, nullptr, nullptr, 256, 512, 2, 0.f);
    // VQ: 3 stages, emits ZQ bf16 + losses[1..3]
    vq_mfma<<<1024, 512, 0, stream>>>(Zf, Cbf, cn, C0, C1, C2, ZQ, out);
    // G3: H2 = gelu(ZQ @ dW1 + db1)   M=65536 N=512 K=256
    gemm_mfma<0, false><<<2048, 256, 0, stream>>>(
        ZQ, dW1t, db1, H2, nullptr, nullptr, nullptr, 512, 256, 4, 0.f);
    // G4: recon loss                  M=65536 N=1024 K=512
    gemm_mfma<2, false><<<4096, 256, 0, stream>>>(
        H2, dW2t, db2, nullptr, nullptr, x, out, 1024, 512, 8,
        1.0f / (65536.0f * 1024.0f));
}

// Round 5
// 538.974 us; speedup vs baseline: 1.5421x; 1.5421x over previous
//
#include <hip/hip_runtime.h>
#include <cstddef>

// ---------------------------------------------------------------------------
// RQ-VAE forward, bf16-MFMA pipeline.
//   prep:  weights -> Wt bf16 [N][K]; codebooks -> bf16 + f32 norms
//   G1: H1 = gelu(x @ eW1 + eb1)          (A: f32->bf16 in-flight)   -> bf16
//   G2: Z  = H1 @ eW2 + eb2                                           -> f32
//   VQ v5: 512thr/64rows; R f32 in regs (32/thread, no spill);
//       codebook staged 32-code x 256-k tiles via global_load_lds,
//       double-buffered + XOR-swizzled (both-sides rule); wave =
//       (row-group, code-half); emits ZQ = q0+q1+q2 bf16
//   G3: H2 = gelu(ZQ @ dW1 + db1)                                     -> bf16
//   G4: recon = mean((H2 @ dW2 + db2 - x)^2)   (loss-only epilogue)
// ---------------------------------------------------------------------------

typedef __attribute__((ext_vector_type(8))) __bf16 bf16x8;
typedef __attribute__((ext_vector_type(4))) float f32x4;
typedef unsigned short u16;

__device__ __forceinline__ u16 f2bf(float f) {
    unsigned u = __float_as_uint(f);
    u += 0x7fffu + ((u >> 16) & 1u);      // round-to-nearest-even
    return (u16)(u >> 16);
}
__device__ __forceinline__ float gelu_exact(float v) {
    return 0.5f * v * (1.0f + erff(v * 0.7071067811865475f));
}
__device__ __forceinline__ void gload16(const void* g, void* l) {
    __builtin_amdgcn_global_load_lds(
        (const __attribute__((address_space(1))) void*)g,
        (__attribute__((address_space(3))) void*)l, 16, 0, 0);
}
__device__ __forceinline__ f32x4 mfma_bf16(bf16x8 a, bf16x8 b, f32x4 c) {
    return __builtin_amdgcn_mfma_f32_16x16x32_bf16(a, b, c, 0, 0, 0);
}

// ---------------------------------------------------------------------------
// prep: transpose+cast the 4 weights to bf16 [N][K]
__global__ __launch_bounds__(256)
void prep_weights(const float* __restrict__ eW1, const float* __restrict__ eW2,
                  const float* __restrict__ dW1, const float* __restrict__ dW2,
                  u16* __restrict__ eW1t, u16* __restrict__ eW2t,
                  u16* __restrict__ dW1t, u16* __restrict__ dW2t)
{
    const int b = blockIdx.x, t = threadIdx.x;
    if (b < 2048) {                    // eW1 [1024][512] -> [512][1024]
        int e = b * 256 + t;
        int n = e >> 10, k = e & 1023;
        eW1t[e] = f2bf(eW1[(size_t)k * 512 + n]);
    } else if (b < 2560) {             // eW2 [512][256] -> [256][512]
        int e = (b - 2048) * 256 + t;
        int n = e >> 9, k = e & 511;
        eW2t[e] = f2bf(eW2[(size_t)k * 256 + n]);
    } else if (b < 3072) {             // dW1 [256][512] -> [512][256]
        int e = (b - 2560) * 256 + t;
        int n = e >> 8, k = e & 255;
        dW1t[e] = f2bf(dW1[(size_t)k * 512 + n]);
    } else {                           // dW2 [512][1024] -> [1024][512]
        int e = (b - 3072) * 256 + t;
        int n = e >> 9, k = e & 511;
        dW2t[e] = f2bf(dW2[(size_t)k * 1024 + n]);
    }
}

// codebooks: bf16 cast (contiguous [1792][256]) + f32 squared norms
__global__ __launch_bounds__(256)
void cb_prep(const float* __restrict__ C0, const float* __restrict__ C1,
             const float* __restrict__ C2, u16* __restrict__ Cbf,
             float* __restrict__ cnorm)
{
    __shared__ float red[256];
    const int code = blockIdx.x, t = threadIdx.x;
    const float* C;
    int local;
    if (code < 1024)      { C = C0; local = code; }
    else if (code < 1536) { C = C1; local = code - 1024; }
    else                  { C = C2; local = code - 1536; }
    const float v = C[(size_t)local * 256 + t];
    Cbf[(size_t)code * 256 + t] = f2bf(v);
    red[t] = v * v;
    __syncthreads();
    for (int s = 128; s; s >>= 1) { if (t < s) red[t] += red[t + s]; __syncthreads(); }
    if (t == 0) cnorm[code] = red[0];
}

// ---------------------------------------------------------------------------
// MFMA GEMM: C = A[M,K] @ Bt[N,K]^T, 128x128 tile, BK=32, 4 waves, dbuf LDS.
// EPI: 0 = gelu -> bf16 store, 1 = plain -> f32 store, 2 = sq-err loss vs X
// AF32: A is f32, converted to bf16 during staging (reg path).
template <int EPI, bool AF32>
__global__ __launch_bounds__(256, 2)
void gemm_mfma(const void* __restrict__ Aptr, const u16* __restrict__ Bt,
               const float* __restrict__ bias, u16* __restrict__ Obf,
               float* __restrict__ Of, const float* __restrict__ X,
               float* __restrict__ lossOut, int N, int K, int ntn,
               float lossScale)
{
    __shared__ __align__(16) u16 As[2][128 * 32];
    __shared__ __align__(16) u16 Bs[2][128 * 32];

    const int nwg = gridDim.x;
    const int bid = blockIdx.x;
    const int wg  = (bid & 7) * (nwg >> 3) + (bid >> 3);   // XCD-chunked swizzle
    const int brow = (wg / ntn) * 128;
    const int bcol = (wg % ntn) * 128;

    const int t    = threadIdx.x;
    const int lane = t & 63;
    const int wid  = t >> 6;
    const int wrow = (wid >> 1) * 64, wcol = (wid & 1) * 64;
    const int lrow = lane & 15, lk8 = (lane >> 4) * 8;

    const int nt = K >> 5;   // K-steps of 32

    f32x4 acc[4][4];
#pragma unroll
    for (int m = 0; m < 4; ++m)
#pragma unroll
        for (int n = 0; n < 4; ++n) acc[m][n] = (f32x4)0.f;

    const u16*   Abf = (const u16*)Aptr;
    const float* Af  = (const float*)Aptr;

    // ---- staging helpers ----
    auto stageB = [&](int kt, int buf) {
#pragma unroll
        for (int it = 0; it < 2; ++it) {
            const int e0 = (it * 256 + t) * 8;
            const int row = e0 >> 5, col = e0 & 31;
            gload16(&Bt[(size_t)(bcol + row) * K + kt * 32 + col],
                    (char*)&Bs[buf][0] + (size_t)e0 * 2);
        }
    };
    auto stageA_bf = [&](int kt, int buf) {
#pragma unroll
        for (int it = 0; it < 2; ++it) {
            const int e0 = (it * 256 + t) * 8;
            const int row = e0 >> 5, col = e0 & 31;
            gload16(&Abf[(size_t)(brow + row) * K + kt * 32 + col],
                    (char*)&As[buf][0] + (size_t)e0 * 2);
        }
    };
    auto issueA_f32 = [&](int kt, float4* r) {
#pragma unroll
        for (int it = 0; it < 4; ++it) {
            const int e0 = (it * 256 + t) * 4;
            const int row = e0 >> 5, col = e0 & 31;
            r[it] = *(const float4*)&Af[(size_t)(brow + row) * K + kt * 32 + col];
        }
    };
    auto writeA_f32 = [&](int buf, const float4* r) {
#pragma unroll
        for (int it = 0; it < 4; ++it) {
            const int e0 = (it * 256 + t) * 4;
            const float4 v = r[it];
            unsigned lo = (unsigned)f2bf(v.x) | ((unsigned)f2bf(v.y) << 16);
            unsigned hi = (unsigned)f2bf(v.z) | ((unsigned)f2bf(v.w) << 16);
            *(uint2*)((char*)&As[buf][0] + (size_t)e0 * 2) = make_uint2(lo, hi);
        }
    };

    // ---- prologue ----
    if (AF32) {
        float4 r0[4];
        issueA_f32(0, r0);
        stageB(0, 0);
        writeA_f32(0, r0);
    } else {
        stageA_bf(0, 0);
        stageB(0, 0);
    }
    __syncthreads();

    int cur = 0;
    for (int kt = 0; kt < nt; ++kt) {
        const bool last = (kt == nt - 1);
        float4 rnext[4];
        if (!last) {
            if (AF32) issueA_f32(kt + 1, rnext);
            else      stageA_bf(kt + 1, cur ^ 1);
            stageB(kt + 1, cur ^ 1);
        }
        // compute current buffer
        bf16x8 a[4], b[4];
#pragma unroll
        for (int m = 0; m < 4; ++m)
            a[m] = *(const bf16x8*)&As[cur][(wrow + m * 16 + lrow) * 32 + lk8];
#pragma unroll
        for (int n = 0; n < 4; ++n)
            b[n] = *(const bf16x8*)&Bs[cur][(wcol + n * 16 + lrow) * 32 + lk8];
#pragma unroll
        for (int m = 0; m < 4; ++m)
#pragma unroll
            for (int n = 0; n < 4; ++n)
                acc[m][n] = mfma_bf16(a[m], b[n], acc[m][n]);

        if (AF32 && !last) writeA_f32(cur ^ 1, rnext);
        __syncthreads();
        cur ^= 1;
    }

    // ---- epilogue ----
    int   colN[4];
    float bn[4];
#pragma unroll
    for (int n = 0; n < 4; ++n) {
        colN[n] = bcol + wcol + n * 16 + lrow;
        bn[n]   = bias[colN[n]];
    }

    if (EPI == 0) {
#pragma unroll
        for (int m = 0; m < 4; ++m) {
            const int rowb = brow + wrow + m * 16 + (lane >> 4) * 4;
#pragma unroll
            for (int n = 0; n < 4; ++n)
#pragma unroll
                for (int j = 0; j < 4; ++j)
                    Obf[(size_t)(rowb + j) * N + colN[n]] =
                        f2bf(gelu_exact(acc[m][n][j] + bn[n]));
        }
    } else if (EPI == 1) {
#pragma unroll
        for (int m = 0; m < 4; ++m) {
            const int rowb = brow + wrow + m * 16 + (lane >> 4) * 4;
#pragma unroll
            for (int n = 0; n < 4; ++n)
#pragma unroll
                for (int j = 0; j < 4; ++j)
                    Of[(size_t)(rowb + j) * N + colN[n]] = acc[m][n][j] + bn[n];
        }
    } else {
        float partial = 0.f;
#pragma unroll
        for (int m = 0; m < 4; ++m) {
            const int rowb = brow + wrow + m * 16 + (lane >> 4) * 4;
#pragma unroll
            for (int n = 0; n < 4; ++n)
#pragma unroll
                for (int j = 0; j < 4; ++j) {
                    const float o = acc[m][n][j] + bn[n];
                    const float d = o - X[(size_t)(rowb + j) * N + colN[n]];
                    partial = fmaf(d, d, partial);
                }
        }
        float* red = (float*)&As[0][0];
        red[t] = partial;
        __syncthreads();
        for (int s = 128; s; s >>= 1) { if (t < s) red[t] += red[t + s]; __syncthreads(); }
        if (t == 0) atomicAdd(lossOut, red[0] * lossScale);
    }
}

// ---------------------------------------------------------------------------
// VQ v5: 512 threads, 64 rows/block. Thread (col = t&255, rh = t>>8) owns
// rows rh*32..rh*32+31 of its column -> R[32] f32 in regs.
// 8 waves = 4 row-groups x 2 code-halves. Per stage:
//   - bf16 mirror of R into LDS; wave loads its 16-row A-frags to regs
//   - codebook tiles (32 codes x 256 k = 16KB) staged via global_load_lds,
//     double-buffered; XOR swizzle (row&7)<<4 on pre-swizzled global source,
//     mirrored on the ds_read side (both-sides rule)
//   - per tile: 8 ds_read_b128 + 8 MFMA per wave, one barrier per tile
//   - wave argmin over 16 code-lanes, cross-half combine in LDS
//   - f32 residual update + commit loss (shfl + 8-slot reduce)
// Final: ZQ = C0[i0]+C1[i1]+C2[i2] (no Z re-read).
__global__ __launch_bounds__(512, 4)
void vq_mfma(const float* __restrict__ Z, const u16* __restrict__ Cbf,
             const float* __restrict__ cnorm,
             const float* __restrict__ C0, const float* __restrict__ C1,
             const float* __restrict__ C2,
             u16* __restrict__ ZQ, float* __restrict__ lossOut)
{
    __shared__ __align__(16) u16 Rb[64][264];      // 33.8 KB residual mirror
    __shared__ __align__(16) u16 Cs[2][32 * 256];  // 2 x 16 KB code tiles
    __shared__ float redv[64][2];
    __shared__ int   redi[64][2];
    __shared__ int   idxs[3][64];
    __shared__ float lred[8];

    const int t    = threadIdx.x;
    const int lane = t & 63;
    const int wid  = t >> 6;           // 0..7
    const int rg   = wid & 3;          // row group (16 rows)
    const int cg   = wid >> 2;         // code half
    const int lrow = lane & 15, g = lane >> 4;
    const int col  = t & 255;          // owned column
    const int rh   = t >> 8;           // row half (32 rows)
    const int brow = blockIdx.x * 64;

    float R[32];
#pragma unroll
    for (int r = 0; r < 32; ++r)
        R[r] = Z[(size_t)(brow + rh * 32 + r) * 256 + col];

    const float* Cf[3]  = {C0, C1, C2};
    const int ncodes[3] = {1024, 512, 256};
    const int coff[3]   = {0, 1024, 1536};
    const float lscale  = 1.25f / (65536.0f * 256.0f);

    for (int stage = 0; stage < 3; ++stage) {
        const u16*   Cb  = Cbf + (size_t)coff[stage] * 256;
        const float* cns = cnorm + coff[stage];
        const int ntile  = ncodes[stage] >> 5;

        // stage a 32-code x 256-k tile (16 KB) into Cs[buf]; LDS dest linear
        // (gload_lds), XOR swizzle applied on the GLOBAL source.
        auto stageC = [&](int tile, int buf) {
#pragma unroll
            for (int it = 0; it < 2; ++it) {
                const int d   = (it * 512 + t) * 16;   // dest byte in 16KB buf
                const int row = d >> 9;                // 0..31
                const int kb  = d & 511;
                const int kbs = kb ^ ((row & 7) << 4);
                gload16(&Cb[(size_t)(tile * 32 + row) * 256 + (kbs >> 1)],
                        (char*)&Cs[buf][0] + d);
            }
        };

        stageC(0, 0);                     // overlap first staging with mirror
#pragma unroll
        for (int r = 0; r < 32; ++r) Rb[rh * 32 + r][col] = f2bf(R[r]);
        __syncthreads();

        // wave's 16 rows -> A fragments in registers for the whole stage
        bf16x8 a[8];
#pragma unroll
        for (int ks = 0; ks < 8; ++ks)
            a[ks] = *(const bf16x8*)&Rb[rg * 16 + lrow][ks * 32 + g * 8];

        float best[4]; int bidx[4];
#pragma unroll
        for (int j = 0; j < 4; ++j) { best[j] = 3.0e38f; bidx[j] = 0; }

        const int cr = cg * 16 + lrow;    // this lane's code row within tile

        int buf = 0;
#pragma unroll 1
        for (int tile = 0; tile < ntile; ++tile) {
            if (tile + 1 < ntile) stageC(tile + 1, buf ^ 1);
            const int   code = tile * 32 + cr;
            const float cn   = cns[code];
            f32x4 acc = (f32x4)0.f;
#pragma unroll
            for (int ks = 0; ks < 8; ++ks) {
                const int kb = (ks * 64 + g * 16) ^ ((cr & 7) << 4);
                bf16x8 b = *(const bf16x8*)((const char*)&Cs[buf][0]
                             + cr * 512 + kb);
                acc = mfma_bf16(a[ks], b, acc);
            }
#pragma unroll
            for (int j = 0; j < 4; ++j) {
                const float s = fmaf(-2.0f, acc[j], cn);
                if (s < best[j]) { best[j] = s; bidx[j] = code; }
            }
            __syncthreads();              // staging done + buf free
            buf ^= 1;
        }

        // argmin: 16 code-lanes within wave, then across the 2 code-halves
#pragma unroll
        for (int j = 0; j < 4; ++j) {
            float v = best[j]; int i = bidx[j];
#pragma unroll
            for (int d = 1; d < 16; d <<= 1) {
                const float ov = __shfl_xor(v, d);
                const int   oi = __shfl_xor(i, d);
                if (ov < v || (ov == v && oi < i)) { v = ov; i = oi; }
            }
            if (lrow == 0) {
                redv[rg * 16 + g * 4 + j][cg] = v;
                redi[rg * 16 + g * 4 + j][cg] = i;
            }
        }
        __syncthreads();
        if (t < 64) {
            float v = redv[t][0]; int i = redi[t][0];
            const float ov = redv[t][1]; const int oi = redi[t][1];
            if (ov < v || (ov == v && oi < i)) { v = ov; i = oi; }
            idxs[stage][t] = i;
        }
        __syncthreads();

        // residual update + commit loss (f32, thread owns its column)
        const float* Cfs = Cf[stage];
        float partial = 0.f;
#pragma unroll
        for (int r = 0; r < 32; ++r) {
            const float q  = Cfs[(size_t)idxs[stage][rh * 32 + r] * 256 + col];
            const float rn = R[r] - q;
            R[r] = rn;
            partial = fmaf(rn, rn, partial);
        }
#pragma unroll
        for (int d = 32; d; d >>= 1) partial += __shfl_down(partial, d);
        if (lane == 0) lred[wid] = partial;
        __syncthreads();
        if (t == 0) {
            float s = 0.f;
#pragma unroll
            for (int w2 = 0; w2 < 8; ++w2) s += lred[w2];
            atomicAdd(&lossOut[1 + stage], s * lscale);
        }
        __syncthreads();
    }

    // ZQ = q0 + q1 + q2 (f32 gather from L2-resident codebooks), bf16
#pragma unroll
    for (int r = 0; r < 32; ++r) {
        const int row = rh * 32 + r;
        const float zq = C0[(size_t)idxs[0][row] * 256 + col]
                       + C1[(size_t)idxs[1][row] * 256 + col]
                       + C2[(size_t)idxs[2][row] * 256 + col];
        ZQ[(size_t)(brow + row) * 256 + col] = f2bf(zq);
    }
}

// ---------------------------------------------------------------------------
extern "C" void kernel_launch(void* const* d_in, const int* in_sizes, int n_in,
                              void* d_out, int out_size, void* d_ws, size_t ws_size,
                              hipStream_t stream)
{
    const float* x   = (const float*)d_in[0];
    const float* eW1 = (const float*)d_in[1];
    const float* eb1 = (const float*)d_in[2];
    const float* eW2 = (const float*)d_in[3];
    const float* eb2 = (const float*)d_in[4];
    const float* dW1 = (const float*)d_in[5];
    const float* db1 = (const float*)d_in[6];
    const float* dW2 = (const float*)d_in[7];
    const float* db2 = (const float*)d_in[8];
    const float* C0  = (const float*)d_in[9];
    const float* C1  = (const float*)d_in[10];
    const float* C2  = (const float*)d_in[11];
    float* out = (float*)d_out;

    char* w = (char*)d_ws;
    u16*   H1   = (u16*)(w);                          // 64 MiB
    float* Zf   = (float*)(w + ((size_t)64 << 20));   // 64 MiB
    u16*   ZQ   = (u16*)(w + ((size_t)128 << 20));    // 32 MiB
    u16*   H2   = (u16*)(w + ((size_t)160 << 20));    // 64 MiB
    u16*   eW1t = (u16*)(w + ((size_t)224 << 20));
    u16*   eW2t = (u16*)(w + ((size_t)225 << 20));
    u16*   dW1t = (u16*)(w + ((size_t)226 << 20));
    u16*   dW2t = (u16*)(w + ((size_t)227 << 20));
    u16*   Cbf  = (u16*)(w + ((size_t)228 << 20));
    float* cn   = (float*)(w + ((size_t)229 << 20));

    hipMemsetAsync(d_out, 0, 4 * sizeof(float), stream);

    prep_weights<<<5120, 256, 0, stream>>>(eW1, eW2, dW1, dW2, eW1t, eW2t, dW1t, dW2t);
    cb_prep<<<1792, 256, 0, stream>>>(C0, C1, C2, Cbf, cn);

    // G1: H1 = gelu(x @ eW1 + eb1)    M=65536 N=512 K=1024, A f32
    gemm_mfma<0, true><<<2048, 256, 0, stream>>>(
        x, eW1t, eb1, H1, nullptr, nullptr, nullptr, 512, 1024, 4, 0.f);
    // G2: Z = H1 @ eW2 + eb2          M=65536 N=256 K=512
    gemm_mfma<1, false><<<1024, 256, 0, stream>>>(
        H1, eW2t, eb2, nullptr, Zf, nullptr, nullptr, 256, 512, 2, 0.f);
    // VQ: 3 stages, emits ZQ bf16 + losses[1..3]
    vq_mfma<<<1024, 512, 0, stream>>>(Zf, Cbf, cn, C0, C1, C2, ZQ, out);
    // G3: H2 = gelu(ZQ @ dW1 + db1)   M=65536 N=512 K=256
    gemm_mfma<0, false><<<2048, 256, 0, stream>>>(
        ZQ, dW1t, db1, H2, nullptr, nullptr, nullptr, 512, 256, 4, 0.f);
    // G4: recon loss                  M=65536 N=1024 K=512
    gemm_mfma<2, false><<<4096, 256, 0, stream>>>(
        H2, dW2t, db2, nullptr, nullptr, x, out, 1024, 512, 8,
        1.0f / (65536.0f * 1024.0f));
}